// Round 13
// baseline (6961.792 us; speedup 1.0000x reference)
//
#include <hip/hip_runtime.h>
#include <math.h>

// Problem constants
#define B_   64
#define S_   512
#define D_   256
#define H_   512
#define G4   2048
#define K0   768
#define K1   1024
#define NWG  256
#define NAH  128
#define NTHR 512            // 8 waves -> 2 waves/SIMD (R12 was 4 -> 1/SIMD, zero TLP)
#define BH   32768          // B_*H_
#define NROT 4

// ws layout (float/uint indices)
#define OFF_SCL  192
#define OFF_FLG  512        // 256 startup-gbar flags x16
#define OFF_EPO  4608
#define OFF_TKT  4736
#define OFF_XCN  5120       // per-XCD xbar counters 8x16
#define OFF_PFL  5248       // 256 producer round-tag flags x16
#define OFF_H0   9344
#define OFF_H1   (OFF_H0 + 2*BH)
#define OFF_C0   (OFF_H1 + 2*BH)
#define OFF_C1   (OFF_C0 + BH)
#define OFF_ZEND (OFF_C1 + BH)
#define OFF_XBUF OFF_ZEND               // per-XCD: [8][NROT] slots of 4BH shorts
#define XBUF_SZ  (8 * NROT * 2 * BH)    // floats
#define OFF_END  (OFF_XBUF + XBUF_SZ)

typedef __attribute__((ext_vector_type(4))) float f32x4;
typedef __attribute__((ext_vector_type(8))) short s16x8;
typedef __attribute__((ext_vector_type(4))) short s16x4;

__device__ __forceinline__ float sigm(float v){ return 1.0f/(1.0f+expf(-v)); }
__device__ __forceinline__ unsigned short f2bf(float f){
  unsigned u = __builtin_bit_cast(unsigned, f);
  return (unsigned short)((u + 0x7FFFu + ((u>>16)&1u)) >> 16);   // RNE
}
__device__ __forceinline__ float bf2f(unsigned short s){
  return __builtin_bit_cast(float, ((unsigned)s) << 16);
}
__device__ __forceinline__ void split8(const float* v, s16x8& h, s16x8& l){
#pragma unroll
  for (int e = 0; e < 8; ++e){
    unsigned short hs = f2bf(v[e]);
    h[e] = (short)hs;
    l[e] = (short)f2bf(v[e] - bf2f(hs));
  }
}
__device__ __forceinline__ void split4(const f32x4& v, s16x4& h, s16x4& l){
#pragma unroll
  for (int e = 0; e < 4; ++e){
    unsigned short hs = f2bf(v[e]);
    h[e] = (short)hs;
    l[e] = (short)f2bf(v[e] - bf2f(hs));
  }
}

// sc1 (IF$-point) relaxed atomics -- cross-XCD safe.
#define ALD(p)   __hip_atomic_load((p), __ATOMIC_RELAXED, __HIP_MEMORY_SCOPE_AGENT)
#define AST(p,v) __hip_atomic_store((p), (v), __ATOMIC_RELAXED, __HIP_MEMORY_SCOPE_AGENT)

// Intra-XCD: atomic RMWs execute at local L2 (never stale). R7-proven.
__device__ __forceinline__ void xadd_noret(unsigned* p, unsigned v){
  asm volatile("global_atomic_add %0, %1, off\n\ts_waitcnt vmcnt(0)"
               :: "v"(p), "v"(v) : "memory");
}
__device__ __forceinline__ unsigned xadd_ret0(unsigned* p){
  unsigned r, z = 0u;
  asm volatile("global_atomic_add %0, %1, %2, off sc0\n\ts_waitcnt vmcnt(0)"
               : "=&v"(r) : "v"(p), "v"(z) : "memory");
  return r;
}
// h publication: sc1 atomic swap executes AT the IF$ -> vmcnt ack == visible.
// (R11 used plain sc1 stores: acked before IF$ visibility -> stale-read race.)
__device__ __forceinline__ void hpub_sc1(float* p, float v){
  unsigned b = __builtin_bit_cast(unsigned, v);
  asm volatile("global_atomic_swap %0, %1, off sc1\n\ts_waitcnt vmcnt(0)"
               :: "v"(p), "v"(b) : "memory");
}
// one 16B sc1 load (IF$-fresh).
__device__ __forceinline__ void ld1x4_sc1(const float* p, f32x4& a){
  asm volatile("global_load_dwordx4 %0, %1, off sc1\n\ts_waitcnt vmcnt(0)"
               : "=&v"(a) : "v"(p) : "memory");
}

__global__ void lstm_init(const float* __restrict__ efw, float* __restrict__ ws){
  int stride = gridDim.x * blockDim.x;
  for (int j = blockIdx.x * blockDim.x + threadIdx.x; j < OFF_ZEND; j += stride){
    float v = 0.0f;
    if (j >= OFF_SCL && j < OFF_SCL + D_) v = expf(efw[j - OFF_SCL]);
    ws[j] = v;
  }
}

__launch_bounds__(NTHR, 1)
__global__ void lstm_persist(const float* __restrict__ x,
                             const float* __restrict__ W0,
                             const float* __restrict__ b0,
                             const float* __restrict__ W1,
                             const float* __restrict__ b1,
                             float* __restrict__ out,
                             float* __restrict__ ws)
{
  // Fragment-linear LDS (lane l touches byte l*16 of each 1KB block):
  __shared__ short wfH[32*64*8];      // 32KB  W hi frags
  __shared__ short wfL[32*64*8];      // 32KB  W lo frags
  __shared__ short afH2[2][16*64*8];  // 32KB  A hi frags, double-buffered
  __shared__ short afL2[2][16*64*8];  // 32KB  A lo frags
  __shared__ float zB[2][64*17];      // 8.7KB gate partials per K-half
  __shared__ float scl[D_];           // 1KB   exp(efw)
  __shared__ int   sslot;             // ~138KB -> 1 WG/CU, 8 waves = 2/SIMD

  const int  wg  = blockIdx.x;
  const int  tid = threadIdx.x;
  const bool isA = (wg < NAH);
  const int  u0  = (isA ? wg : wg - NAH) * 4;
  const int  KI  = isA ? 24 : 32;
  const int  nch = isA ? 6 : 8;
  const int  lane = tid & 63;
  const int  wv_  = tid >> 6;        // 0..7
  const int  rb   = wv_ & 3;         // row-block (16 rows)
  const int  kh   = wv_ >> 2;        // K-half (2 of 4 ki-slices per chunk)

  float* h0 = ws + OFF_H0;
  float* h1 = ws + OFF_H1;
  float* cs = ws + (isA ? OFF_C0 : OFF_C1);
  short* XB = (short*)(ws + OFF_XBUF);
  unsigned* epo = (unsigned*)ws + OFF_EPO;
  unsigned* flg = (unsigned*)ws + OFF_FLG;
  unsigned* tkt = (unsigned*)ws + OFF_TKT;
  unsigned* pfl = (unsigned*)ws + OFF_PFL;

  // One-time: W -> split-bf16 fragments (B-frag: col=l%16, k=ki*32+(l/16)*8+e).
  {
    const float* W = isA ? W0 : W1;
    for (int f = tid; f < KI*64; f += NTHR){
      int ki = f >> 6, ln = f & 63;
      int col = ln & 15, g = col >> 2, u2 = col & 3;
      int kb = ki*32 + ((ln >> 4) << 3);
      const float* wp = W + (size_t)kb * G4 + g * H_ + u0 + u2;
      s16x8 hh, ll;
#pragma unroll
      for (int e = 0; e < 8; ++e){
        float w = wp[(size_t)e * G4];
        unsigned short hs = f2bf(w);
        hh[e] = (short)hs;
        ll[e] = (short)f2bf(w - bf2f(hs));
      }
      *(s16x8*)&wfH[(size_t)f * 8] = hh;
      *(s16x8*)&wfL[(size_t)f * 8] = ll;
    }
  }
  for (int i = tid; i < D_; i += NTHR) scl[i] = ws[OFF_SCL + i];

  // XCD identity + slot ticket (agent RMW at IF$, one-time).
  int xcc, slot, nx = 1;
  {
    xcc = (int)(__builtin_amdgcn_s_getreg(63508) & 7u);  // HW_REG_XCC_ID
    if (tid == 0)
      sslot = (int)__hip_atomic_fetch_add(tkt + (size_t)xcc*16, 1u,
                 __ATOMIC_RELAXED, __HIP_MEMORY_SCOPE_AGENT);
    __syncthreads();
    slot = sslot;
  }
  unsigned* xcnt = (unsigned*)ws + OFF_XCN + (size_t)xcc*16;

  // ---- startup-only global barrier (R4-proven sc1 flags, tag 1) ----
  auto gbar = [&](unsigned tgt){
    __syncthreads();
    if (tid == 0) AST(flg + (size_t)wg * 16, tgt);
    if (wg == 0 && tid < 64){
      for (;;){
        unsigned m0 = ALD(flg + (size_t)(tid       ) * 16);
        unsigned m1 = ALD(flg + (size_t)(tid +  64) * 16);
        unsigned m2 = ALD(flg + (size_t)(tid + 128) * 16);
        unsigned m3 = ALD(flg + (size_t)(tid + 192) * 16);
        if (__all(m0 >= tgt && m1 >= tgt && m2 >= tgt && m3 >= tgt)) break;
      }
      if (tid == 0){
#pragma unroll
        for (int kq = 0; kq < 8; ++kq) AST(epo + (size_t)kq * 16, tgt);
      }
    }
    if (tid < 64){
      while (ALD(epo + (size_t)(wg & 7) * 16) < tgt)
        __builtin_amdgcn_s_sleep(4);
    }
    __syncthreads();
  };

  // ---- XCD-local barrier (R7-proven L2 atomic counter) ----
  auto xbar = [&](unsigned ev){
    __syncthreads();                  // staging stores drained into local L2
    if (tid == 0){
      xadd_noret(xcnt, 1u);
      const unsigned tgt = ev * (unsigned)nx;
      while (xadd_ret0(xcnt) < tgt) __builtin_amdgcn_s_sleep(1);
    }
    __syncthreads();
  };

  gbar(1u);                           // tickets final + init zeros visible
  nx = (int)ALD(tkt + (size_t)xcc * 16);

  // Dataflow stager, layer-split: waves 0-3 poll the 4 A-producers of column
  // group g and pull h0; waves 4-7 poll the 4 B-producers and pull h1. No
  // intra-stage barrier -> h0 staging overlaps B's compute tail (A ends
  // earlier: nch 6 vs 8). One dwordx4 sc1 load per thread per slice.
  auto stage_round = [&](int q, int rot, unsigned tag){
    short* sbw = XB + ((size_t)(xcc * NROT + rot)) * (4 * (size_t)BH);
    const int half = kh;              // 0: h0, 1: h1
    for (int g = slot; g < 32; g += nx){
      int fidx = (lane < 4) ? ((half ? NAH : 0) + 4*g + lane) : -1;
      unsigned v = tag;
      for (;;){
        if (fidx >= 0) v = ALD(pfl + (size_t)fidx * 16);
        if (__all(v >= tag)) break;
        __builtin_amdgcn_s_sleep(1);
      }
      const int rw  = rb * 16 + (lane >> 2);
      const int col = 16*g + (lane & 3) * 4;
      const float* src = ws + (half ? OFF_H1 : OFF_H0) + (size_t)q * BH
                       + (size_t)rw * H_ + col;
      f32x4 a; ld1x4_sc1(src, a);
      s16x4 hi, lo; split4(a, hi, lo);
      size_t o = (size_t)rw * H_ + col;
      *(s16x4*)(sbw + (size_t)half * BH + o)       = hi;  // h0 hi|h1 hi
      *(s16x4*)(sbw + (size_t)(2 + half) * BH + o) = lo;  // h0 lo|h1 lo
    }
  };

  stage_round(1, 3, 0u);              // pre-stage parity-1 zeros (tag 0: no wait)
  xbar(1u);

  // update-phase roles + bias (valid for tid<256)
  const int row_r = tid & 63;
  const int uu    = (tid >> 6) & 3;
  float bias[4];
  {
    const float* bv = isA ? b0 : b1;
#pragma unroll
    for (int g = 0; g < 4; ++g) bias[g] = bv[g * H_ + u0 + uu];
  }
  __syncthreads();

  const short* sb = nullptr;
  s16x8 rh[2], rl[2];                 // 2 frag-slots per thread (was 4 @256thr)
  const int r16 = lane & 15, ksl = lane >> 4;

  // Load chunk c (CK=128): thread covers slots sidx = jj*8+wv_, jj in {0,1};
  // slot sidx -> (j=sidx>>2 row-block, ki=sidx&3); elems k=c*128+ki*32+ksl*8.
  auto loadregs = [&](int c, int t){
#pragma unroll
    for (int jj = 0; jj < 2; ++jj){
      const int sidx = jj * 8 + wv_;
      const int j = sidx >> 2, ki = sidx & 3;
      const int kk = c * 128 + ki * 32 + ksl * 8;
      const int row = 16 * j + r16;
      if (isA && kk < 256){                       // x part (scaled), split here
        const float* xp = x + ((size_t)row * S_ + t) * D_ + kk;
        float4 v0 = *(const float4*)xp;
        float4 v1 = *(const float4*)(xp + 4);
        float4 s0 = *(const float4*)&scl[kk];
        float4 s1 = *(const float4*)&scl[kk + 4];
        float v[8] = {v0.x*s0.x, v0.y*s0.y, v0.z*s0.z, v0.w*s0.w,
                      v1.x*s1.x, v1.y*s1.y, v1.z*s1.z, v1.w*s1.w};
        split8(v, rh[jj], rl[jj]);
      } else {                                    // h: pre-split bf16 in xbuf
        const short* hp;
        if (isA)           hp = sb + (size_t)row * H_ + (kk - 256);
        else if (kk < 512) hp = sb + (size_t)row * H_ + kk;
        else               hp = sb + BH + (size_t)row * H_ + (kk - 512);
        rh[jj] = *(const s16x8*)hp;
        rl[jj] = *(const s16x8*)(hp + 2 * BH);
      }
    }
  };
  auto writefrags = [&](int b){
#pragma unroll
    for (int jj = 0; jj < 2; ++jj){
      const int fs = ((jj * 8 + wv_) * 64 + lane) * 8;
      *(s16x8*)&afH2[b][fs] = rh[jj];
      *(s16x8*)&afL2[b][fs] = rl[jj];
    }
  };

  for (int r = 0; r <= S_; ++r){
    const bool act = isA ? (r < S_) : (r >= 1);
    if (act){
      const int t = isA ? r : r - 1;
      sb = (const short*)(XB + ((size_t)(xcc * NROT + ((r + 3) & 3))) * (4 * (size_t)BH));
      f32x4 aHH = {0.f,0.f,0.f,0.f}, aHL = aHH, aLH = aHH;
      loadregs(0, t);
      writefrags(0);                  // afrag[0] free (prior round drained)

      for (int c = 0; c < nch; ++c){
        __syncthreads();              // afrag[c&1] ready; afrag[(c+1)&1] free
        if (c + 1 < nch){ loadregs(c + 1, t); writefrags((c + 1) & 1); }
        const short* aH = afH2[c & 1];
        const short* aL = afL2[c & 1];
#pragma unroll
        for (int ki2 = 0; ki2 < 2; ++ki2){
          const int ki = kh * 2 + ki2;
          int as  = ((rb * 4 + ki) * 64 + lane) * 8;
          int wsl = ((c * 4 + ki) * 64 + lane) * 8;
          s16x8 ah = *(const s16x8*)&aH[as];
          s16x8 al = *(const s16x8*)&aL[as];
          s16x8 wh = *(const s16x8*)&wfH[wsl];
          s16x8 wl = *(const s16x8*)&wfL[wsl];
          aHH = __builtin_amdgcn_mfma_f32_16x16x32_bf16(ah, wh, aHH, 0, 0, 0);
          aHL = __builtin_amdgcn_mfma_f32_16x16x32_bf16(ah, wl, aHL, 0, 0, 0);
          aLH = __builtin_amdgcn_mfma_f32_16x16x32_bf16(al, wh, aLH, 0, 0, 0);
        }
      }

      // C-frag (col=lane&15, row=(lane>>4)*4+reg) -> per-K-half zB slab
      f32x4 accs = (aHH + aHL) + aLH;
#pragma unroll
      for (int reg = 0; reg < 4; ++reg){
        int row = 16 * rb + ((lane >> 4) << 2) + reg;
        zB[kh][row * 17 + (lane & 15)] = accs[reg];
      }
      __syncthreads();
      if (tid < 256){
        float z[4];
#pragma unroll
        for (int g = 0; g < 4; ++g)
          z[g] = zB[0][row_r * 17 + g * 4 + uu]
               + zB[1][row_r * 17 + g * 4 + uu] + bias[g];
        const int ui = u0 + uu;
        float c_ = cs[(size_t)row_r * H_ + ui];
        float i_ = sigm(z[0]);
        float f_ = sigm(z[1] + c_) * 0.9f;        // decayed forget (DECAY=0.1)
        float g_ = tanhf(z[2]);
        float o_ = sigm(z[3]);
        float cn = f_ * c_ + i_ * g_;
        float hn = o_ * tanhf(cn);
        cs[(size_t)row_r * H_ + ui] = cn;
        if (!isA) out[((size_t)row_r * S_ + t) * H_ + ui] = hn;
        float* hw = (isA ? h0 : h1) + (size_t)(r & 1) * BH + (size_t)row_r * H_ + ui;
        hpub_sc1(hw, hn);             // atomic swap: visible at IF$ at ack
      }
    }

    if (r < S_){
      __syncthreads();                // all h-swaps acked AT the IF$
      if (tid == 0) AST(pfl + (size_t)wg * 16, (unsigned)(r + 2));  // publish
      stage_round(r & 1, r & 3, (unsigned)(r + 2));  // pull deps as they land
      xbar((unsigned)(r + 2));                       // local release
    }
  }
}

extern "C" void kernel_launch(void* const* d_in, const int* in_sizes, int n_in,
                              void* d_out, int out_size, void* d_ws, size_t ws_size,
                              hipStream_t stream){
  const float* x   = (const float*)d_in[0];
  const float* W0  = (const float*)d_in[1];
  const float* b0  = (const float*)d_in[2];
  const float* W1  = (const float*)d_in[3];
  const float* b1  = (const float*)d_in[4];
  const float* efw = (const float*)d_in[5];
  float* out = (float*)d_out;
  float* ws  = (float*)d_ws;

  if (ws_size < (size_t)OFF_END * sizeof(float)) return;  // ~9.2 MB scratch

  lstm_init<<<256, 256, 0, stream>>>(efw, ws);
  lstm_persist<<<NWG, NTHR, 0, stream>>>(x, W0, b0, W1, b1, out, ws);
}